// Round 4
// baseline (1049.713 us; speedup 1.0000x reference)
//
#include <hip/hip_runtime.h>

typedef unsigned short u16;
typedef short s8v __attribute__((ext_vector_type(8)));   // 8 x bf16 bits (4 VGPRs)
typedef float f32x4 __attribute__((ext_vector_type(4)));

#define MFMA16(a, b, c) __builtin_amdgcn_mfma_f32_16x16x32_bf16((a), (b), (c), 0, 0, 0)
#define GLDS16(gp, lp)                                                         \
  __builtin_amdgcn_global_load_lds(                                            \
      (const __attribute__((address_space(1))) void*)(gp),                     \
      (__attribute__((address_space(3))) void*)(lp), 16, 0, 0)

__device__ __forceinline__ float bf2f(u16 u) {
  unsigned int i = ((unsigned int)u) << 16;
  float f;
  __builtin_memcpy(&f, &i, 4);
  return f;
}
__device__ __forceinline__ u16 f2bf(float f) {
  unsigned int u;
  __builtin_memcpy(&u, &f, 4);
  unsigned int r = (u + 0x7FFFu + ((u >> 16) & 1u)) >> 16;  // RNE
  return (u16)r;
}

// ---------------- f32 -> bf16 convert (activations) -------------------------
__global__ __launch_bounds__(256) void cvt_f32_bf16(const float* __restrict__ s,
                                                    u16* __restrict__ d, long n) {
  long i = ((long)blockIdx.x * 256 + threadIdx.x) * 4;
  if (i + 3 < n) {
    float4 v = *(const float4*)(s + i);
    ushort4 o;
    o.x = f2bf(v.x); o.y = f2bf(v.y); o.z = f2bf(v.z); o.w = f2bf(v.w);
    *(ushort4*)(d + i) = o;
  }
}

// ------- 2048x2048 transpose + convert (weights f32 K-major -> bf16 N-major)
__global__ __launch_bounds__(256) void transpose2048(const float* __restrict__ W,
                                                     u16* __restrict__ Wt) {
  __shared__ u16 t[64][65];
  int c0 = blockIdx.x * 64, r0 = blockIdx.y * 64;
  int x = threadIdx.x & 63, y = threadIdx.x >> 6;
  for (int yy = y; yy < 64; yy += 4)
    t[yy][x] = f2bf(W[(long)(r0 + yy) * 2048 + c0 + x]);
  __syncthreads();
  for (int yy = y; yy < 64; yy += 4)
    Wt[(long)(c0 + yy) * 2048 + r0 + x] = t[x][yy];
}

// ---------------- GEMM: Y[M x N] = A[M x 2048] * Bt^T + bias ----------------
// DUAL=1: n in [2048,4096) goes to Yv2/bias2 (two fused output tensors).
template <int OUTF, int DUAL>
__global__ __launch_bounds__(256, 2) void gemm_bias_bt(
    const u16* __restrict__ A, const u16* __restrict__ Bt,
    const float* __restrict__ bias, const float* __restrict__ bias2,
    void* __restrict__ Yv, void* __restrict__ Yv2, int M, int rpb, int bstride,
    int roff) {
  __shared__ u16 smA[128 * 32];
  __shared__ u16 smB[128 * 32];
  const int tid = threadIdx.x;
  const int wave = tid >> 6, lane = tid & 63;
  const int lo = lane & 15, qd = lane >> 4;
  const int m0 = blockIdx.x * 128, n0 = blockIdx.y * 128;
  const int wm = (wave & 1) * 64, wn = (wave >> 1) * 64;

  const u16* aG[2];
  const u16* bG[2];
  u16* aL[2];
  u16* bL[2];
#pragma unroll
  for (int r = 0; r < 2; ++r) {
    int c = (wave * 2 + r) * 64 + lane;  // 16B chunk id, c = row*4 + seg
    int row = c >> 2, seg = c & 3;
    int gr = m0 + row;
    if (gr > M - 1) gr = M - 1;
    long grow = (long)(gr / rpb) * bstride + roff + (gr % rpb);
    aG[r] = A + grow * 2048 + seg * 8;
    bG[r] = Bt + (long)(n0 + row) * 2048 + seg * 8;
    aL[r] = smA + (wave * 2 + r) * 512;  // wave-uniform LDS base
    bL[r] = smB + (wave * 2 + r) * 512;
  }

  f32x4 acc[4][4] = {};
  for (int k0 = 0; k0 < 2048; k0 += 32) {
    GLDS16(aG[0] + k0, aL[0]);
    GLDS16(aG[1] + k0, aL[1]);
    GLDS16(bG[0] + k0, bL[0]);
    GLDS16(bG[1] + k0, bL[1]);
    __syncthreads();
    s8v af[4], bf[4];
#pragma unroll
    for (int i = 0; i < 4; i++)
      af[i] = *(const s8v*)(smA + (wm + i * 16 + lo) * 32 + qd * 8);
#pragma unroll
    for (int i = 0; i < 4; i++)
      bf[i] = *(const s8v*)(smB + (wn + i * 16 + lo) * 32 + qd * 8);
#pragma unroll
    for (int i = 0; i < 4; i++)
#pragma unroll
      for (int j = 0; j < 4; j++) acc[i][j] = MFMA16(af[i], bf[j], acc[i][j]);
    __syncthreads();
  }
#pragma unroll
  for (int j = 0; j < 4; j++) {
    int nf = n0 + wn + j * 16 + lo;
    const float* bp = bias;
    void* yp = Yv;
    int n = nf;
    if (DUAL && nf >= 2048) {
      bp = bias2;
      yp = Yv2;
      n = nf - 2048;
    }
    float bv = bp[n];
#pragma unroll
    for (int i = 0; i < 4; i++) {
      int mb = m0 + wm + i * 16 + qd * 4;
#pragma unroll
      for (int r = 0; r < 4; r++) {
        int m = mb + r;
        if (m < M) {
          float val = acc[i][j][r] + bv;
          if (OUTF)
            ((float*)yp)[(long)m * 2048 + n] = val;
          else
            ((u16*)yp)[(long)m * 2048 + n] = f2bf(val);
        }
      }
    }
  }
}

// ---------------- RMS norm over rows of 2048 (bf16 in place, f32 scale) -----
__global__ __launch_bounds__(256) void rmsnorm_rows(u16* __restrict__ X,
                                                    const float* __restrict__ sc) {
  long row = blockIdx.x;
  u16* xr = X + row * 2048;
  int tid = threadIdx.x;
  s8v v = *(const s8v*)(xr + tid * 8);
  float f[8], ss = 0.f;
#pragma unroll
  for (int j = 0; j < 8; j++) {
    f[j] = bf2f((u16)v[j]);
    ss += f[j] * f[j];
  }
  for (int o = 1; o < 64; o <<= 1) ss += __shfl_xor(ss, o);
  __shared__ float wsum[4];
  if ((tid & 63) == 0) wsum[tid >> 6] = ss;
  __syncthreads();
  float tot = wsum[0] + wsum[1] + wsum[2] + wsum[3];
  float rs = rsqrtf(tot * (1.f / 2048.f) + 1e-6f);
  float4 s0 = *(const float4*)(sc + tid * 8);
  float4 s1 = *(const float4*)(sc + tid * 8 + 4);
  float scv[8] = {s0.x, s0.y, s0.z, s0.w, s1.x, s1.y, s1.z, s1.w};
  s8v o8;
#pragma unroll
  for (int j = 0; j < 8; j++) o8[j] = (short)f2bf(f[j] * rs * scv[j]);
  *(s8v*)(xr + tid * 8) = o8;
}

// ---------------- V repack: V[b][l][h][d] -> VT[b][h][d][l] (zero-pad l) ----
__global__ __launch_bounds__(256) void repack_vt(const u16* __restrict__ V,
                                                 u16* __restrict__ VT, int L,
                                                 int Lpad) {
  int bh = blockIdx.z;  // b*16 + h
  int b = bh >> 4, h = bh & 15;
  int l0 = blockIdx.x * 64, d0 = blockIdx.y * 64;
  __shared__ u16 t[64][65];
  int x = threadIdx.x & 63, y = threadIdx.x >> 6;
  for (int yy = y; yy < 64; yy += 4) {
    int l = l0 + yy;
    u16 val = 0;
    if (l < L) val = V[((long)(b * L + l)) * 2048 + h * 128 + d0 + x];
    t[yy][x] = val;
  }
  __syncthreads();
  for (int yy = y; yy < 64; yy += 4) {
    int d = d0 + yy;
    int l = l0 + x;
    if (l < Lpad) VT[((long)bh * 128 + d) * Lpad + l] = t[x][yy];
  }
}

// ---------------- single-phase cross-attention ------------------------------
// 32 queries/wave. Fixed-offset softmax: p = exp(s*sc - 12) (exact; per-lane
// denominator reduced once at the end). No block barriers; wave-private,
// parity-double-buffered P slice in LDS; DS in-order within a wave makes the
// store->read safe without an explicit fence (compiler emits lgkmcnt).
// L/LPAD/NT compile-time so the tile loop fully unrolls and the scheduler can
// pipeline tile k+1's K/V loads over tile k's exp/LDS chain.
template <int ADD, int L, int LPAD, int NT>
__global__ __launch_bounds__(256, 4) void cross_attn(
    const u16* __restrict__ Q, const u16* __restrict__ K,
    const u16* __restrict__ VT, u16* __restrict__ O) {
  const int tid = threadIdx.x, wave = tid >> 6, lane = tid & 63;
  const int lo = lane & 15, qd = lane >> 4;
  const int h = blockIdx.y, b = blockIdx.z;
  const int q0 = blockIdx.x * 128 + wave * 32;
  __shared__ u16 pls[4][2][1280];  // [wave][parity][32 q x stride 40]

  const u16* Kb = K + ((long)b * L) * 2048 + h * 128;
  const u16* VTb = VT + ((long)(b * 16 + h)) * 128 * LPAD;

  s8v aq[2][4];
#pragma unroll
  for (int qf = 0; qf < 2; ++qf) {
    const u16* qp =
        Q + ((long)(b * 4096 + q0 + qf * 16 + lo)) * 2048 + h * 128 + qd * 8;
#pragma unroll
    for (int ds = 0; ds < 4; ++ds) aq[qf][ds] = *(const s8v*)(qp + ds * 32);
  }

  const float SC = 0.08838834764831845f;  // 1/sqrt(128)
  f32x4 oacc[2][8] = {};
  float lsum[2][4] = {};

#pragma unroll
  for (int kt = 0; kt < NT; ++kt) {
    // ---- K fragments (q-independent) ----
    s8v bk[2][4];
#pragma unroll
    for (int nf = 0; nf < 2; ++nf) {
      int key = kt * 32 + nf * 16 + lo;
      int keyc = key < L ? key : L - 1;
      const u16* kp = Kb + (long)keyc * 2048 + qd * 8;
#pragma unroll
      for (int ds = 0; ds < 4; ++ds) bk[nf][ds] = *(const s8v*)(kp + ds * 32);
    }
    // ---- QK^T ----
    f32x4 sacc[2][2] = {};
#pragma unroll
    for (int qf = 0; qf < 2; ++qf)
#pragma unroll
      for (int nf = 0; nf < 2; ++nf)
#pragma unroll
        for (int ds = 0; ds < 4; ++ds)
          sacc[qf][nf] = MFMA16(aq[qf][ds], bk[nf][ds], sacc[qf][nf]);
    // ---- exp (fixed offset), accumulate denominator, P -> LDS ----
    u16* pw = pls[wave][kt & 1];
#pragma unroll
    for (int qf = 0; qf < 2; ++qf)
#pragma unroll
      for (int nf = 0; nf < 2; ++nf) {
        int key = kt * 32 + nf * 16 + lo;
        bool msk = key >= L;
#pragma unroll
        for (int r = 0; r < 4; ++r) {
          float s = fminf(fmaf(sacc[qf][nf][r], SC, -12.f), 50.f);
          float p = msk ? 0.f : __expf(s);
          lsum[qf][r] += p;
          pw[(qf * 16 + qd * 4 + r) * 40 + nf * 16 + lo] = f2bf(p);
        }
      }
    s8v pa[2];
#pragma unroll
    for (int qf = 0; qf < 2; ++qf)
      pa[qf] = *(const s8v*)(pw + (qf * 16 + lo) * 40 + qd * 8);
    // ---- P * V ----
    const u16* vp = VTb + (long)lo * LPAD + kt * 32 + qd * 8;
#pragma unroll
    for (int df = 0; df < 8; ++df) {
      s8v bv = *(const s8v*)(vp + (long)df * 16 * LPAD);
      oacc[0][df] = MFMA16(pa[0], bv, oacc[0][df]);
      oacc[1][df] = MFMA16(pa[1], bv, oacc[1][df]);
    }
  }
  // ---- denominator reduce (over the 16 key-lanes) + output ----
#pragma unroll
  for (int qf = 0; qf < 2; ++qf)
#pragma unroll
    for (int r = 0; r < 4; ++r) {
      float l = lsum[qf][r];
      for (int o = 1; o < 16; o <<= 1) l += __shfl_xor(l, o);
      lsum[qf][r] = 1.f / l;
    }
  u16* op = O + ((long)(b * 4096 + q0)) * 2048 + h * 128;
#pragma unroll
  for (int qf = 0; qf < 2; ++qf)
#pragma unroll
    for (int df = 0; df < 8; ++df) {
      int d = df * 16 + lo;
#pragma unroll
      for (int r = 0; r < 4; ++r) {
        long idx = (long)(qf * 16 + qd * 4 + r) * 2048 + d;
        float val = oacc[qf][df][r] * lsum[qf][r];
        if (ADD) val += bf2f(op[idx]);
        op[idx] = f2bf(val);
      }
    }
}

extern "C" void kernel_launch(void* const* d_in, const int* in_sizes, int n_in,
                              void* d_out, int out_size, void* d_ws,
                              size_t ws_size, hipStream_t stream) {
  const float* x = (const float*)d_in[0];
  const float* ctx = (const float*)d_in[1];
  const float* q_w = (const float*)d_in[2];
  const float* q_b = (const float*)d_in[3];
  const float* k_w = (const float*)d_in[4];
  const float* k_b = (const float*)d_in[5];
  const float* v_w = (const float*)d_in[6];
  const float* v_b = (const float*)d_in[7];
  const float* ki_w = (const float*)d_in[8];
  const float* ki_b = (const float*)d_in[9];
  const float* vi_w = (const float*)d_in[10];
  const float* vi_b = (const float*)d_in[11];
  const float* o_w = (const float*)d_in[12];
  const float* o_b = (const float*)d_in[13];
  const float* nq_s = (const float*)d_in[14];
  const float* nkt_s = (const float*)d_in[15];
  const float* nki_s = (const float*)d_in[16];
  float* out = (float*)d_out;
  u16* ws = (u16*)d_ws;

  // workspace layout (u16 elements); total ~103 MB
  u16* w0 = ws;                        //  4,194,304 (w0|w1 contiguous = 4096-row cat)
  u16* w1 = ws + 4194304L;             //  4,194,304
  u16* q = ws + 8388608L;              // 16,777,216
  u16* attn = ws + 25165824L;          // 16,777,216
  u16* xb = attn;                      // alias (dead before attn written)
  u16* vtxt = attn;                    // alias, 2,097,152
  u16* vimg = attn + 2097152L;         // alias, 1,052,672
  u16* ktxt = ws + 41943040L;          //  2,097,152
  u16* kimg = ws + 44040192L;          //  1,052,672
  u16* vttxt = ws + 45092864L;         //  2,097,152 (32 x 128 x 512)
  u16* vtimg = ws + 47190016L;         //  1,179,648 (32 x 128 x 288)
  u16* ctxb = ws + 48369664L;          //  3,149,824

  dim3 tb(256);
  dim3 tg(32, 32);

  cvt_f32_bf16<<<16384, tb, 0, stream>>>(x, xb, 16777216L);
  cvt_f32_bf16<<<3076, tb, 0, stream>>>(ctx, ctxb, 3149824L);

  transpose2048<<<tg, tb, 0, stream>>>(q_w, w0);
  gemm_bias_bt<0, 0><<<dim3(64, 16), tb, 0, stream>>>(
      xb, w0, q_b, nullptr, q, nullptr, 8192, 4096, 4096, 0);

  // K|V txt fused (N=4096): Bt rows 0..2047 = k_w^T, 2048..4095 = v_w^T
  transpose2048<<<tg, tb, 0, stream>>>(k_w, w0);
  transpose2048<<<tg, tb, 0, stream>>>(v_w, w1);
  gemm_bias_bt<0, 1><<<dim3(8, 32), tb, 0, stream>>>(
      ctxb, w0, k_b, v_b, ktxt, vtxt, 1024, 512, 769, 257);

  // Ki|Vi img fused
  transpose2048<<<tg, tb, 0, stream>>>(ki_w, w0);
  transpose2048<<<tg, tb, 0, stream>>>(vi_w, w1);
  gemm_bias_bt<0, 1><<<dim3(5, 32), tb, 0, stream>>>(
      ctxb, w0, ki_b, vi_b, kimg, vimg, 514, 257, 769, 0);

  rmsnorm_rows<<<8192, tb, 0, stream>>>(q, nq_s);
  rmsnorm_rows<<<1024, tb, 0, stream>>>(ktxt, nkt_s);
  rmsnorm_rows<<<514, tb, 0, stream>>>(kimg, nki_s);

  repack_vt<<<dim3(8, 2, 32), tb, 0, stream>>>(vtxt, vttxt, 512, 512);
  repack_vt<<<dim3(5, 2, 32), tb, 0, stream>>>(vimg, vtimg, 257, 288);

  // txt phase writes attn; img phase adds its (separately-normalized) result
  cross_attn<0, 512, 512, 16><<<dim3(32, 16, 2), tb, 0, stream>>>(q, ktxt, vttxt, attn);
  cross_attn<1, 257, 288, 9><<<dim3(32, 16, 2), tb, 0, stream>>>(q, kimg, vtimg, attn);

  transpose2048<<<tg, tb, 0, stream>>>(o_w, w0);
  gemm_bias_bt<1, 0><<<dim3(64, 16), tb, 0, stream>>>(
      attn, w0, o_b, nullptr, out, nullptr, 8192, 4096, 4096, 0);
}

// Round 5
// 843.012 us; speedup vs baseline: 1.2452x; 1.2452x over previous
//
#include <hip/hip_runtime.h>

typedef unsigned short u16;
typedef short s8v __attribute__((ext_vector_type(8)));   // 8 x bf16 bits (4 VGPRs)
typedef float f32x4 __attribute__((ext_vector_type(4)));

#define MFMA16(a, b, c) __builtin_amdgcn_mfma_f32_16x16x32_bf16((a), (b), (c), 0, 0, 0)
#define GLDS16(gp, lp)                                                         \
  __builtin_amdgcn_global_load_lds(                                            \
      (const __attribute__((address_space(1))) void*)(gp),                     \
      (__attribute__((address_space(3))) void*)(lp), 16, 0, 0)

__device__ __forceinline__ float bf2f(u16 u) {
  unsigned int i = ((unsigned int)u) << 16;
  float f;
  __builtin_memcpy(&f, &i, 4);
  return f;
}
__device__ __forceinline__ u16 f2bf(float f) {
  unsigned int u;
  __builtin_memcpy(&u, &f, 4);
  unsigned int r = (u + 0x7FFFu + ((u >> 16) & 1u)) >> 16;  // RNE
  return (u16)r;
}

// ---------------- f32 -> bf16 convert (activations) -------------------------
__global__ __launch_bounds__(256) void cvt_f32_bf16(const float* __restrict__ s,
                                                    u16* __restrict__ d, long n) {
  long i = ((long)blockIdx.x * 256 + threadIdx.x) * 4;
  if (i + 3 < n) {
    float4 v = *(const float4*)(s + i);
    ushort4 o;
    o.x = f2bf(v.x); o.y = f2bf(v.y); o.z = f2bf(v.z); o.w = f2bf(v.w);
    *(ushort4*)(d + i) = o;
  }
}

// ------- 2048x2048 transpose + convert (weights f32 K-major -> bf16 N-major)
__global__ __launch_bounds__(256) void transpose2048(const float* __restrict__ W,
                                                     u16* __restrict__ Wt) {
  __shared__ u16 t[64][65];
  int c0 = blockIdx.x * 64, r0 = blockIdx.y * 64;
  int x = threadIdx.x & 63, y = threadIdx.x >> 6;
  for (int yy = y; yy < 64; yy += 4)
    t[yy][x] = f2bf(W[(long)(r0 + yy) * 2048 + c0 + x]);
  __syncthreads();
  for (int yy = y; yy < 64; yy += 4)
    Wt[(long)(c0 + yy) * 2048 + r0 + x] = t[x][yy];
}

// ---------------- GEMM: Y[M x N] = A[M x 2048] * Bt^T + bias ----------------
// DUAL=1: n in [2048,4096) goes to Yv2/bias2 (two fused output tensors).
template <int OUTF, int DUAL>
__global__ __launch_bounds__(256, 2) void gemm_bias_bt(
    const u16* __restrict__ A, const u16* __restrict__ Bt,
    const float* __restrict__ bias, const float* __restrict__ bias2,
    void* __restrict__ Yv, void* __restrict__ Yv2, int M, int rpb, int bstride,
    int roff) {
  __shared__ u16 smA[128 * 32];
  __shared__ u16 smB[128 * 32];
  const int tid = threadIdx.x;
  const int wave = tid >> 6, lane = tid & 63;
  const int lo = lane & 15, qd = lane >> 4;
  const int m0 = blockIdx.x * 128, n0 = blockIdx.y * 128;
  const int wm = (wave & 1) * 64, wn = (wave >> 1) * 64;

  const u16* aG[2];
  const u16* bG[2];
  u16* aL[2];
  u16* bL[2];
#pragma unroll
  for (int r = 0; r < 2; ++r) {
    int c = (wave * 2 + r) * 64 + lane;  // 16B chunk id, c = row*4 + seg
    int row = c >> 2, seg = c & 3;
    int gr = m0 + row;
    if (gr > M - 1) gr = M - 1;
    long grow = (long)(gr / rpb) * bstride + roff + (gr % rpb);
    aG[r] = A + grow * 2048 + seg * 8;
    bG[r] = Bt + (long)(n0 + row) * 2048 + seg * 8;
    aL[r] = smA + (wave * 2 + r) * 512;  // wave-uniform LDS base
    bL[r] = smB + (wave * 2 + r) * 512;
  }

  f32x4 acc[4][4] = {};
  for (int k0 = 0; k0 < 2048; k0 += 32) {
    GLDS16(aG[0] + k0, aL[0]);
    GLDS16(aG[1] + k0, aL[1]);
    GLDS16(bG[0] + k0, bL[0]);
    GLDS16(bG[1] + k0, bL[1]);
    __syncthreads();
    s8v af[4], bf[4];
#pragma unroll
    for (int i = 0; i < 4; i++)
      af[i] = *(const s8v*)(smA + (wm + i * 16 + lo) * 32 + qd * 8);
#pragma unroll
    for (int i = 0; i < 4; i++)
      bf[i] = *(const s8v*)(smB + (wn + i * 16 + lo) * 32 + qd * 8);
#pragma unroll
    for (int i = 0; i < 4; i++)
#pragma unroll
      for (int j = 0; j < 4; j++) acc[i][j] = MFMA16(af[i], bf[j], acc[i][j]);
    __syncthreads();
  }
#pragma unroll
  for (int j = 0; j < 4; j++) {
    int nf = n0 + wn + j * 16 + lo;
    const float* bp = bias;
    void* yp = Yv;
    int n = nf;
    if (DUAL && nf >= 2048) {
      bp = bias2;
      yp = Yv2;
      n = nf - 2048;
    }
    float bv = bp[n];
#pragma unroll
    for (int i = 0; i < 4; i++) {
      int mb = m0 + wm + i * 16 + qd * 4;
#pragma unroll
      for (int r = 0; r < 4; r++) {
        int m = mb + r;
        if (m < M) {
          float val = acc[i][j][r] + bv;
          if (OUTF)
            ((float*)yp)[(long)m * 2048 + n] = val;
          else
            ((u16*)yp)[(long)m * 2048 + n] = f2bf(val);
        }
      }
    }
  }
}

// ---------------- RMS norm over rows of 2048 (bf16 in place, f32 scale) -----
__global__ __launch_bounds__(256) void rmsnorm_rows(u16* __restrict__ X,
                                                    const float* __restrict__ sc) {
  long row = blockIdx.x;
  u16* xr = X + row * 2048;
  int tid = threadIdx.x;
  s8v v = *(const s8v*)(xr + tid * 8);
  float f[8], ss = 0.f;
#pragma unroll
  for (int j = 0; j < 8; j++) {
    f[j] = bf2f((u16)v[j]);
    ss += f[j] * f[j];
  }
  for (int o = 1; o < 64; o <<= 1) ss += __shfl_xor(ss, o);
  __shared__ float wsum[4];
  if ((tid & 63) == 0) wsum[tid >> 6] = ss;
  __syncthreads();
  float tot = wsum[0] + wsum[1] + wsum[2] + wsum[3];
  float rs = rsqrtf(tot * (1.f / 2048.f) + 1e-6f);
  float4 s0 = *(const float4*)(sc + tid * 8);
  float4 s1 = *(const float4*)(sc + tid * 8 + 4);
  float scv[8] = {s0.x, s0.y, s0.z, s0.w, s1.x, s1.y, s1.z, s1.w};
  s8v o8;
#pragma unroll
  for (int j = 0; j < 8; j++) o8[j] = (short)f2bf(f[j] * rs * scv[j]);
  *(s8v*)(xr + tid * 8) = o8;
}

// ---------------- V repack: V[b][l][h][d] -> VT[b][h][d][l] (zero-pad l) ----
__global__ __launch_bounds__(256) void repack_vt(const u16* __restrict__ V,
                                                 u16* __restrict__ VT, int L,
                                                 int Lpad) {
  int bh = blockIdx.z;  // b*16 + h
  int b = bh >> 4, h = bh & 15;
  int l0 = blockIdx.x * 64, d0 = blockIdx.y * 64;
  __shared__ u16 t[64][65];
  int x = threadIdx.x & 63, y = threadIdx.x >> 6;
  for (int yy = y; yy < 64; yy += 4) {
    int l = l0 + yy;
    u16 val = 0;
    if (l < L) val = V[((long)(b * L + l)) * 2048 + h * 128 + d0 + x];
    t[yy][x] = val;
  }
  __syncthreads();
  for (int yy = y; yy < 64; yy += 4) {
    int d = d0 + yy;
    int l = l0 + x;
    if (l < Lpad) VT[((long)bh * 128 + d) * Lpad + l] = t[x][yy];
  }
}

// ---------------- single-phase cross-attention ------------------------------
// 32 queries/wave. Fixed-offset softmax: p = exp(s*sc - 12) (exact; per-lane
// denominator reduced once at the end). No block barriers; wave-private,
// parity-double-buffered P slice in LDS (same-buffer aliasing keeps the
// compiler from reordering the ds store->read; it emits the lgkmcnt).
// Rolled loop + unroll 2: small scheduling window -> no spill (round-4
// full-unroll + 128-reg cap spilled oacc: WRITE_SIZE 33->788 MB).
// launch_bounds(256,3): cap 170 regs total (oacc 64 AGPR + aq 16 + ~75 live)
// -> 3 waves/SIMD instead of round-3's 2 (172 total regs).
template <int ADD, int L, int LPAD, int NT>
__global__ __launch_bounds__(256, 3) void cross_attn(
    const u16* __restrict__ Q, const u16* __restrict__ K,
    const u16* __restrict__ VT, u16* __restrict__ O) {
  const int tid = threadIdx.x, wave = tid >> 6, lane = tid & 63;
  const int lo = lane & 15, qd = lane >> 4;
  const int h = blockIdx.y, b = blockIdx.z;
  const int q0 = blockIdx.x * 128 + wave * 32;
  __shared__ u16 pls[4][2][1280];  // [wave][parity][32 q x stride 40]

  const u16* Kb = K + ((long)b * L) * 2048 + h * 128;
  const u16* VTb = VT + ((long)(b * 16 + h)) * 128 * LPAD;

  s8v aq[2][4];
#pragma unroll
  for (int qf = 0; qf < 2; ++qf) {
    const u16* qp =
        Q + ((long)(b * 4096 + q0 + qf * 16 + lo)) * 2048 + h * 128 + qd * 8;
#pragma unroll
    for (int ds = 0; ds < 4; ++ds) aq[qf][ds] = *(const s8v*)(qp + ds * 32);
  }

  const float SC = 0.08838834764831845f;  // 1/sqrt(128)
  f32x4 oacc[2][8] = {};
  float lsum[2][4] = {};

#pragma unroll 2
  for (int kt = 0; kt < NT; ++kt) {
    // ---- K fragments (q-independent) ----
    s8v bk[2][4];
#pragma unroll
    for (int nf = 0; nf < 2; ++nf) {
      int key = kt * 32 + nf * 16 + lo;
      int keyc = key < L ? key : L - 1;
      const u16* kp = Kb + (long)keyc * 2048 + qd * 8;
#pragma unroll
      for (int ds = 0; ds < 4; ++ds) bk[nf][ds] = *(const s8v*)(kp + ds * 32);
    }
    // ---- QK^T ----
    f32x4 sacc[2][2] = {};
#pragma unroll
    for (int qf = 0; qf < 2; ++qf)
#pragma unroll
      for (int nf = 0; nf < 2; ++nf)
#pragma unroll
        for (int ds = 0; ds < 4; ++ds)
          sacc[qf][nf] = MFMA16(aq[qf][ds], bk[nf][ds], sacc[qf][nf]);
    // ---- exp (fixed offset), accumulate denominator, P -> LDS ----
    u16* pw = pls[wave][kt & 1];
#pragma unroll
    for (int qf = 0; qf < 2; ++qf)
#pragma unroll
      for (int nf = 0; nf < 2; ++nf) {
        int key = kt * 32 + nf * 16 + lo;
        bool msk = key >= L;
#pragma unroll
        for (int r = 0; r < 4; ++r) {
          float s = fminf(fmaf(sacc[qf][nf][r], SC, -12.f), 50.f);
          float p = msk ? 0.f : __expf(s);
          lsum[qf][r] += p;
          pw[(qf * 16 + qd * 4 + r) * 40 + nf * 16 + lo] = f2bf(p);
        }
      }
    s8v pa[2];
#pragma unroll
    for (int qf = 0; qf < 2; ++qf)
      pa[qf] = *(const s8v*)(pw + (qf * 16 + lo) * 40 + qd * 8);
    // ---- P * V ----
    const u16* vp = VTb + (long)lo * LPAD + kt * 32 + qd * 8;
#pragma unroll
    for (int df = 0; df < 8; ++df) {
      s8v bv = *(const s8v*)(vp + (long)df * 16 * LPAD);
      oacc[0][df] = MFMA16(pa[0], bv, oacc[0][df]);
      oacc[1][df] = MFMA16(pa[1], bv, oacc[1][df]);
    }
  }
  // ---- denominator reduce (over the 16 key-lanes) + output ----
#pragma unroll
  for (int qf = 0; qf < 2; ++qf)
#pragma unroll
    for (int r = 0; r < 4; ++r) {
      float l = lsum[qf][r];
      for (int o = 1; o < 16; o <<= 1) l += __shfl_xor(l, o);
      lsum[qf][r] = 1.f / l;
    }
  u16* op = O + ((long)(b * 4096 + q0)) * 2048 + h * 128;
#pragma unroll
  for (int qf = 0; qf < 2; ++qf)
#pragma unroll
    for (int df = 0; df < 8; ++df) {
      int d = df * 16 + lo;
#pragma unroll
      for (int r = 0; r < 4; ++r) {
        long idx = (long)(qf * 16 + qd * 4 + r) * 2048 + d;
        float val = oacc[qf][df][r] * lsum[qf][r];
        if (ADD) val += bf2f(op[idx]);
        op[idx] = f2bf(val);
      }
    }
}

extern "C" void kernel_launch(void* const* d_in, const int* in_sizes, int n_in,
                              void* d_out, int out_size, void* d_ws,
                              size_t ws_size, hipStream_t stream) {
  const float* x = (const float*)d_in[0];
  const float* ctx = (const float*)d_in[1];
  const float* q_w = (const float*)d_in[2];
  const float* q_b = (const float*)d_in[3];
  const float* k_w = (const float*)d_in[4];
  const float* k_b = (const float*)d_in[5];
  const float* v_w = (const float*)d_in[6];
  const float* v_b = (const float*)d_in[7];
  const float* ki_w = (const float*)d_in[8];
  const float* ki_b = (const float*)d_in[9];
  const float* vi_w = (const float*)d_in[10];
  const float* vi_b = (const float*)d_in[11];
  const float* o_w = (const float*)d_in[12];
  const float* o_b = (const float*)d_in[13];
  const float* nq_s = (const float*)d_in[14];
  const float* nkt_s = (const float*)d_in[15];
  const float* nki_s = (const float*)d_in[16];
  float* out = (float*)d_out;
  u16* ws = (u16*)d_ws;

  // workspace layout (u16 elements); total ~103 MB
  u16* w0 = ws;                        //  4,194,304
  u16* w1 = ws + 4194304L;             //  4,194,304
  u16* q = ws + 8388608L;              // 16,777,216
  u16* attn = ws + 25165824L;          // 16,777,216
  u16* xb = attn;                      // alias (dead before attn written)
  u16* vtxt = attn;                    // alias, 2,097,152
  u16* vimg = attn + 2097152L;         // alias, 1,052,672
  u16* ktxt = ws + 41943040L;          //  2,097,152
  u16* kimg = ws + 44040192L;          //  1,052,672
  u16* vttxt = ws + 45092864L;         //  2,097,152 (32 x 128 x 512)
  u16* vtimg = ws + 47190016L;         //  1,179,648 (32 x 128 x 288)
  u16* ctxb = ws + 48369664L;          //  3,149,824

  dim3 tb(256);
  dim3 tg(32, 32);

  cvt_f32_bf16<<<16384, tb, 0, stream>>>(x, xb, 16777216L);
  cvt_f32_bf16<<<3076, tb, 0, stream>>>(ctx, ctxb, 3149824L);

  transpose2048<<<tg, tb, 0, stream>>>(q_w, w0);
  gemm_bias_bt<0, 0><<<dim3(64, 16), tb, 0, stream>>>(
      xb, w0, q_b, nullptr, q, nullptr, 8192, 4096, 4096, 0);

  // K|V txt fused (N=4096): Bt rows 0..2047 = k_w^T, 2048..4095 = v_w^T
  transpose2048<<<tg, tb, 0, stream>>>(k_w, w0);
  transpose2048<<<tg, tb, 0, stream>>>(v_w, w1);
  gemm_bias_bt<0, 1><<<dim3(8, 32), tb, 0, stream>>>(
      ctxb, w0, k_b, v_b, ktxt, vtxt, 1024, 512, 769, 257);

  // Ki|Vi img fused
  transpose2048<<<tg, tb, 0, stream>>>(ki_w, w0);
  transpose2048<<<tg, tb, 0, stream>>>(vi_w, w1);
  gemm_bias_bt<0, 1><<<dim3(5, 32), tb, 0, stream>>>(
      ctxb, w0, ki_b, vi_b, kimg, vimg, 514, 257, 769, 0);

  rmsnorm_rows<<<8192, tb, 0, stream>>>(q, nq_s);
  rmsnorm_rows<<<1024, tb, 0, stream>>>(ktxt, nkt_s);
  rmsnorm_rows<<<514, tb, 0, stream>>>(kimg, nki_s);

  repack_vt<<<dim3(8, 2, 32), tb, 0, stream>>>(vtxt, vttxt, 512, 512);
  repack_vt<<<dim3(5, 2, 32), tb, 0, stream>>>(vimg, vtimg, 257, 288);

  // txt phase writes attn; img phase adds its (separately-normalized) result
  cross_attn<0, 512, 512, 16><<<dim3(32, 16, 2), tb, 0, stream>>>(q, ktxt, vttxt, attn);
  cross_attn<1, 257, 288, 9><<<dim3(32, 16, 2), tb, 0, stream>>>(q, kimg, vtimg, attn);

  transpose2048<<<tg, tb, 0, stream>>>(o_w, w0);
  gemm_bias_bt<1, 0><<<dim3(64, 16), tb, 0, stream>>>(
      attn, w0, o_b, nullptr, out, nullptr, 8192, 4096, 4096, 0);
}